// Round 15
// baseline (1554.679 us; speedup 1.0000x reference)
//
#include <hip/hip_runtime.h>
#include <math.h>

#define H    512
#define OPS  12
#define E    112
#define NWG  128
#define NT   256

typedef unsigned long long u64;
typedef unsigned int u32x4 __attribute__((ext_vector_type(4)));

// ws layout: 16-float header (ws[8] = count) | 2048 tagged u64 | lgacc 4x12 f32
#define TW_HB0   0                    // [2][512] h0n
#define TW_HB1   1024                 // [2][512] h1n
#define TW_TOTAL 2048
#define LG_F     (16 + 2 * TW_TOTAL)  // float offset of lgacc[4][12]

// bank-conflict-reducing row rotation for h-vectors (float4-preserving)
#define SW(j) (((j) & ~31) | (((j) + ((((j) >> 5) & 7) << 2)) & 31))

__device__ __forceinline__ float sigf(float x) { return 1.f / (1.f + expf(-x)); }

// JAX threefry2x32, key = PRNGKey(42) = (0,42), 20 rounds
__device__ __forceinline__ void threefry_42(unsigned x0, unsigned x1,
                                            unsigned& o0, unsigned& o1) {
  const unsigned k0 = 0u, k1 = 42u;
  const unsigned k2 = k0 ^ k1 ^ 0x1BD11BDAu;
  x0 += k0; x1 += k1;
#define TF_R(rot) { x0 += x1; x1 = (x1 << rot) | (x1 >> (32 - rot)); x1 ^= x0; }
  TF_R(13) TF_R(15) TF_R(26) TF_R(6)
  x0 += k1; x1 += k2 + 1u;
  TF_R(17) TF_R(29) TF_R(16) TF_R(24)
  x0 += k2; x1 += k0 + 2u;
  TF_R(13) TF_R(15) TF_R(26) TF_R(6)
  x0 += k0; x1 += k1 + 3u;
  TF_R(17) TF_R(29) TF_R(16) TF_R(24)
  x0 += k1; x1 += k2 + 4u;
  TF_R(13) TF_R(15) TF_R(26) TF_R(6)
  x0 += k2; x1 += k0 + 5u;
#undef TF_R
  o0 = x0; o1 = x1;
}

__device__ __forceinline__ float bits_to_gumbel(unsigned bits) {
  unsigned fb = (bits >> 9) | 0x3f800000u;
  float u = __uint_as_float(fb) - 1.0f;
  u = u + 1.17549435e-38f;
  u = fmaxf(1.17549435e-38f, u);
  return -logf(-logf(u));
}

__device__ __forceinline__ float decode_temp(const void* temp_p) {
  float tf = *(const float*)temp_p;
  float a = fabsf(tf);
  if (a > 1e-6f && a < 1e6f) return tf;
  int ti = *(const int*)temp_p;
  if (ti != 0 && ti > -1000000 && ti < 1000000) return (float)ti;
  double td = *(const double*)temp_p;
  double ad = fabs(td);
  if (ad > 1e-6 && ad < 1e6) return (float)td;
  return 1.0f;
}

// MALL-coherent tagged-word transport (tag<<32 | float bits)
__device__ __forceinline__ void tag_store(u64* p, unsigned tag, float f) {
  u64 v = ((u64)tag << 32) | (u64)__float_as_uint(f);
  __hip_atomic_store(p, v, __ATOMIC_RELAXED, __HIP_MEMORY_SCOPE_SYSTEM);
}
// poll TWO adjacent tagged words with ONE 16B cache-bypassing load
__device__ __forceinline__ void tag_poll2(const u64* p, unsigned tag,
                                          float& f0, float& f1) {
  u32x4 v;
  for (;;) {
    asm volatile("global_load_dwordx4 %0, %1, off sc0 sc1\n\t"
                 "s_waitcnt vmcnt(0)"
                 : "=&v"(v) : "v"(p) : "memory");
    if (v.y == tag && v.w == tag) break;
    __builtin_amdgcn_s_sleep(1);
  }
  f0 = __uint_as_float(v.x);
  f1 = __uint_as_float(v.z);
}

__global__ void k_init(u64* tw, unsigned* cnt) {
  int t = blockIdx.x * blockDim.x + threadIdx.x;
  if (t < TW_TOTAL + 24) tw[t] = 0ull;    // tags + lgacc (24 u64 = 48 f32)
  if (t == 0) *cnt = 0u;
}
__global__ void k_diag(float* out, float v) {
  if (threadIdx.x == 0 && blockIdx.x == 0) out[0] = v;
}

// ===========================================================================
__global__ void __launch_bounds__(NT)
policy_persist(const void* temp_p,
               const float* __restrict__ h0_in, const float* __restrict__ c0_in,
               const float* __restrict__ Wih0,  const float* __restrict__ Whh0,
               const float* __restrict__ bih0,  const float* __restrict__ bhh0,
               const float* __restrict__ Wih1,  const float* __restrict__ Whh1,
               const float* __restrict__ bih1,  const float* __restrict__ bhh1,
               const float* __restrict__ emb,   const float* __restrict__ cW1,
               const float* __restrict__ cb1,   const float* __restrict__ cW2,
               const float* __restrict__ cb2,
               float* __restrict__ out, float* ws) {
  __shared__ __align__(16) float h0full[H], shp1[H];
  __shared__ float g0pre[16], g1bpre[16], g1loc[16];
  __shared__ float ewloc[12 * 16], b0loc[16], b1loc[16];
  __shared__ float gum[E * OPS], cbl[E * OPS];
  __shared__ float w1s[512 * 5];          // W1[i] 4-col slice, stride-5
  __shared__ float w2row[4][OPS];         // W2[i] rows for own 4 cols
  __shared__ float plg[4][OPS];           // per-col partial logits
  __shared__ float lgs[OPS];              // reduced logits (pre-bias)
  __shared__ float c0loc[4], c1loc[4];
  __shared__ float spart[4][4];

  const int tid = threadIdx.x;
  const int bid = blockIdx.x;
  const int j0  = bid * 4;                       // owned h-columns
  const int cb  = (bid & 7) * 16 + (bid >> 3);   // XCD-grouped HM col-block
  const float invt = 1.f / decode_temp(temp_p);

  u64* HB0 = (u64*)(ws + 16) + TW_HB0;
  u64* HB1 = (u64*)(ws + 16) + TW_HB1;
  float*    LG  = ws + LG_F;                     // lgacc[4][12]
  unsigned* cnt = (unsigned*)(ws + 8);

  // ---------------- setup (all WG-local) -----------------------------------
  for (int p = tid; p < E * OPS; p += NT) {
    unsigned y0, y1;
    threefry_42(0u, (unsigned)p, y0, y1);
    gum[p] = bits_to_gumbel(y0 ^ y1);
    cbl[p] = cb2[p];
  }
  for (int j = tid; j < H; j += NT) {
    h0full[SW(j)] = h0_in[j];
    shp1[SW(j)]   = h0_in[H + j];
  }
  if (tid < 192) {
    int a = tid / 16, ridx = tid % 16;
    int g = ridx >> 2, dj = ridx & 3;
    int row = g * H + j0 + dj;
    const float* er = emb + a * H;
    const float* wr = Wih0 + (size_t)row * H;
    float acc = 0.f;
    for (int k = 0; k < H; k += 4) {
      float4 e4 = *(const float4*)(er + k);
      float4 w4 = *(const float4*)(wr + k);
      acc += e4.x * w4.x + e4.y * w4.y + e4.z * w4.z + e4.w * w4.w;
    }
    ewloc[tid] = acc;
  }
  if (tid < 16) {
    int g = tid >> 2, dj = tid & 3;
    int row = g * H + j0 + dj;
    b0loc[tid] = bih0[row] + bhh0[row];
    b1loc[tid] = bih1[row] + bhh1[row];
  }
  if (tid < 4) {
    c0loc[tid] = c0_in[j0 + tid];
    c1loc[tid] = c0_in[H + j0 + tid];
    // W2 rows for step 0 (own 4 cols)
    const float* wsrc = cW2 + (size_t)(cb * 4 + tid) * OPS;
    float4 a = *(const float4*)(wsrc);
    float4 b = *(const float4*)(wsrc + 4);
    float4 c = *(const float4*)(wsrc + 8);
    w2row[tid][0] = a.x; w2row[tid][1] = a.y; w2row[tid][2]  = a.z; w2row[tid][3]  = a.w;
    w2row[tid][4] = b.x; w2row[tid][5] = b.y; w2row[tid][6]  = b.z; w2row[tid][7]  = b.w;
    w2row[tid][8] = c.x; w2row[tid][9] = c.y; w2row[tid][10] = c.z; w2row[tid][11] = c.w;
  }
  __syncthreads();

  // G-pre(0) combined pass + W1[0] prefetch (verified math, swizzled reads)
  {
    int rowidx = tid >> 3, lane = tid & 7;
    int cell = rowidx >> 4, ridx = rowidx & 15;
    int g = ridx >> 2, dj = ridx & 3;
    int row = g * H + j0 + dj;
    const float* wr = (cell ? Whh1 : Whh0) + (size_t)row * H + lane * 64;
    const float* hv = cell ? shp1 : h0full;
    float acc = 0.f;
#pragma unroll
    for (int k = 0; k < 64; k += 4) {
      float4 w4 = *(const float4*)(wr + k);
      float4 h4 = *(const float4*)&hv[SW(lane * 64 + k)];
      acc += w4.x * h4.x + w4.y * h4.y + w4.z * h4.z + w4.w * h4.w;
    }
    acc += __shfl_xor(acc, 1);
    acc += __shfl_xor(acc, 2);
    acc += __shfl_xor(acc, 4);
    if (lane == 0) {
      if (cell == 0) g0pre[ridx] = acc + b0loc[ridx];
      else           g1bpre[ridx] = acc;
    }
    const float* wb = cW1 + (size_t)cb * 4;
    float4 r0 = *(const float4*)(wb + (size_t)tid * H);
    float4 r1 = *(const float4*)(wb + (size_t)(tid + 256) * H);
    int k0 = tid * 5, k1 = (tid + 256) * 5;
    w1s[k0] = r0.x; w1s[k0 + 1] = r0.y; w1s[k0 + 2] = r0.z; w1s[k0 + 3] = r0.w;
    w1s[k1] = r1.x; w1s[k1 + 1] = r1.y; w1s[k1 + 2] = r1.z; w1s[k1 + 3] = r1.w;
  }
  __syncthreads();

#pragma unroll 1
  for (int i = 0; i < E; ++i) {
    const int p = i & 1;
    const unsigned tg = (unsigned)(i + 1);

    // ---- 1: sample step i-1 from reduced logits (count-gated, 12 floats) --
    if (i > 0) {
      const unsigned tgt = 128u * (unsigned)i;
      while (__hip_atomic_load(cnt, __ATOMIC_RELAXED,
                               __HIP_MEMORY_SCOPE_SYSTEM) < tgt)
        __builtin_amdgcn_s_sleep(1);
      if (tid < OPS) {
        lgs[tid] = __hip_atomic_load(&LG[((i - 1) & 3) * OPS + tid],
                                     __ATOMIC_RELAXED, __HIP_MEMORY_SCOPE_SYSTEM);
      }
      __syncthreads();
      // all threads: 12-value logits + argmax (redundant, no reduce needed)
      float lgv[OPS];
#pragma unroll
      for (int o = 0; o < OPS; ++o)
        lgv[o] = (lgs[o] + cbl[(i - 1) * OPS + o]) * invt;
      float best = -1e30f; int act = 0;
#pragma unroll
      for (int o = 0; o < OPS; ++o) {
        float v = lgv[o] + gum[(i - 1) * OPS + o];
        if (v > best) { best = v; act = o; }
      }
      // PW0 (lanes 0-3) + h0n tagged store — critical path head
      if (tid < 4) {
        float gi = g0pre[tid]      + ewloc[act * 16 + tid];
        float gf = g0pre[4 + tid]  + ewloc[act * 16 + 4 + tid];
        float gg = g0pre[8 + tid]  + ewloc[act * 16 + 8 + tid];
        float go = g0pre[12 + tid] + ewloc[act * 16 + 12 + tid];
        float cn = sigf(gf) * c0loc[tid] + sigf(gi) * tanhf(gg);
        c0loc[tid] = cn;
        tag_store(&HB0[p * 512 + j0 + tid], tg, sigf(go) * tanhf(cn));
      }
      // lp/ent/out — off the chain, bid 0 tid 0 only
      if (bid == 0 && tid == 0) {
        float mx = lgv[0];
#pragma unroll
        for (int o = 1; o < OPS; ++o) mx = fmaxf(mx, lgv[o]);
        float se = 0.f;
#pragma unroll
        for (int o = 0; o < OPS; ++o) se += expf(lgv[o] - mx);
        float logZ = mx + logf(se);
        float lp = lgv[act] - logZ;
        float ent = 0.f;
        for (int o = 0; o < OPS; ++o) {
          float l2 = lgv[o] - logZ;
          ent -= expf(l2) * l2;
        }
        out[i - 1]         = (float)act;
        out[E + i - 1]     = lp;
        out[2 * E + i - 1] = ent;
      }
    } else {
      // i == 0: PW0 without embedding contribution
      if (tid < 4) {
        float gi = g0pre[tid];
        float gf = g0pre[4 + tid];
        float gg = g0pre[8 + tid];
        float go = g0pre[12 + tid];
        float cn = sigf(gf) * c0loc[tid] + sigf(gi) * tanhf(gg);
        c0loc[tid] = cn;
        tag_store(&HB0[p * 512 + j0 + tid], tg, sigf(go) * tanhf(cn));
      }
    }

    // ---- 3: poll full h0n (swizzled LDS commit) ---------------------------
    {
      int t2 = tid * 2;
      int sw = SW(t2);
      tag_poll2(&HB0[p * 512 + t2], tg, h0full[sw], h0full[sw + 1]);
    }
    __syncthreads();

    // ---- 4: G1 = Wih1@h0n + G1Bpre + B1 (own 16 rows, 16 lanes/row) -------
    {
      int ridx = tid >> 4, lane = tid & 15;
      int g = ridx >> 2, dj = ridx & 3;
      int row = g * H + j0 + dj;
      const float* wr = Wih1 + (size_t)row * H + lane * 32;
      float acc = 0.f;
#pragma unroll
      for (int k = 0; k < 32; k += 4) {
        float4 w4 = *(const float4*)(wr + k);
        float4 h4 = *(const float4*)&h0full[SW(lane * 32 + k)];
        acc += w4.x * h4.x + w4.y * h4.y + w4.z * h4.z + w4.w * h4.w;
      }
      acc += __shfl_xor(acc, 1);
      acc += __shfl_xor(acc, 2);
      acc += __shfl_xor(acc, 4);
      acc += __shfl_xor(acc, 8);
      if (lane == 0) g1loc[ridx] = acc + g1bpre[ridx] + b1loc[ridx];
    }
    __syncthreads();

    // ---- 5: PW1 (own 4 cols) -> tagged h1n store --------------------------
    if (tid < 4) {
      float gi = g1loc[tid];
      float gf = g1loc[4 + tid];
      float gg = g1loc[8 + tid];
      float go = g1loc[12 + tid];
      float cn = sigf(gf) * c1loc[tid] + sigf(gi) * tanhf(gg);
      c1loc[tid] = cn;
      tag_store(&HB1[p * 512 + j0 + tid], tg, sigf(go) * tanhf(cn));
    }

    // ---- 6: shadow-1: W1[i+1] loads; G0pre(i+1); W2 rows for next C -------
    float4 v0, v1;
    if (i + 1 < E) {
      const float* wb = cW1 + (size_t)(i + 1) * H * H + (size_t)cb * 4;
      v0 = *(const float4*)(wb + (size_t)tid * H);
      v1 = *(const float4*)(wb + (size_t)(tid + 256) * H);
    }
    if (tid < 128) {
      int ridx = tid >> 3, lane = tid & 7;
      int g = ridx >> 2, dj = ridx & 3;
      int row = g * H + j0 + dj;
      const float* wr = Whh0 + (size_t)row * H + lane * 64;
      float acc = 0.f;
#pragma unroll
      for (int k = 0; k < 64; k += 4) {
        float4 w4 = *(const float4*)(wr + k);
        float4 h4 = *(const float4*)&h0full[SW(lane * 64 + k)];
        acc += w4.x * h4.x + w4.y * h4.y + w4.z * h4.z + w4.w * h4.w;
      }
      acc += __shfl_xor(acc, 1);
      acc += __shfl_xor(acc, 2);
      acc += __shfl_xor(acc, 4);
      if (lane == 0) g0pre[ridx] = acc + b0loc[ridx];
    }

    // ---- 7: poll full h1n (swizzled LDS commit) ---------------------------
    {
      int t2 = tid * 2;
      int sw = SW(t2);
      tag_poll2(&HB1[p * 512 + t2], tg, shp1[sw], shp1[sw + 1]);
    }
    __syncthreads();

    // ---- 8: phase C: own 4 HM cols -> partial logits -> global fadd -------
    {
      int wv = tid >> 6, ln = tid & 63;
      int jl = ln & 3, ks = ln >> 2;
      int kbase = wv * 128 + ks * 8;
      float acc = 0.f;
#pragma unroll
      for (int t = 0; t < 8; ++t) {
        int k = kbase + t;
        acc += shp1[SW(k)] * w1s[k * 5 + jl];
      }
      acc += __shfl_xor(acc, 4);
      acc += __shfl_xor(acc, 8);
      acc += __shfl_xor(acc, 16);
      acc += __shfl_xor(acc, 32);
      if (ln < 4) spart[wv][ln] = acc;
    }
    __syncthreads();
    if (tid < 4) {
      float s = spart[0][tid] + spart[1][tid] + spart[2][tid] + spart[3][tid];
      s += cb1[(size_t)i * H + cb * 4 + tid];
      float hmv = fmaxf(s, 0.f);
#pragma unroll
      for (int o = 0; o < OPS; ++o) plg[tid][o] = hmv * w2row[tid][o];
    }
    __syncthreads();
    // WG0 re-zeroes the (i-2) logits buffer for reuse at step i+2
    // (safe window: after all sample(i-1) reads, before any C(i+2) fadd)
    if (bid == 0 && i >= 2 && tid < OPS) {
      __hip_atomic_store(&LG[((i - 2) & 3) * OPS + tid], 0.f,
                         __ATOMIC_RELAXED, __HIP_MEMORY_SCOPE_SYSTEM);
    }
    if (tid < OPS) {
      float ps = ((plg[0][tid] + plg[1][tid]) + plg[2][tid]) + plg[3][tid];
      (void)__hip_atomic_fetch_add(&LG[(i & 3) * OPS + tid], ps,
                                   __ATOMIC_RELAXED, __HIP_MEMORY_SCOPE_SYSTEM);
    }
    asm volatile("s_waitcnt vmcnt(0)" ::: "memory");
    if (tid == 0) {
      (void)__hip_atomic_fetch_add(cnt, 1u, __ATOMIC_RELAXED,
                                   __HIP_MEMORY_SCOPE_SYSTEM);
    }

    // ---- 9: shadow-2: G1Bpre(i+1); commit W1[i+1]; W2 rows for i+1 --------
    if (i + 1 < E) {
      if (tid < 128) {
        int ridx = tid >> 3, lane = tid & 7;
        int g = ridx >> 2, dj = ridx & 3;
        int row = g * H + j0 + dj;
        const float* wr = Whh1 + (size_t)row * H + lane * 64;
        float acc = 0.f;
#pragma unroll
        for (int k = 0; k < 64; k += 4) {
          float4 w4 = *(const float4*)(wr + k);
          float4 h4 = *(const float4*)&shp1[SW(lane * 64 + k)];
          acc += w4.x * h4.x + w4.y * h4.y + w4.z * h4.z + w4.w * h4.w;
        }
        acc += __shfl_xor(acc, 1);
        acc += __shfl_xor(acc, 2);
        acc += __shfl_xor(acc, 4);
        if (lane == 0) g1bpre[ridx] = acc;
      }
      int k0 = tid * 5, k1 = (tid + 256) * 5;
      w1s[k0] = v0.x; w1s[k0 + 1] = v0.y; w1s[k0 + 2] = v0.z; w1s[k0 + 3] = v0.w;
      w1s[k1] = v1.x; w1s[k1 + 1] = v1.y; w1s[k1 + 2] = v1.z; w1s[k1 + 3] = v1.w;
      if (tid < 4) {
        const float* wsrc = cW2 + ((size_t)(i + 1) * H + cb * 4 + tid) * OPS;
        float4 a = *(const float4*)(wsrc);
        float4 b = *(const float4*)(wsrc + 4);
        float4 c = *(const float4*)(wsrc + 8);
        w2row[tid][0] = a.x; w2row[tid][1] = a.y; w2row[tid][2]  = a.z; w2row[tid][3]  = a.w;
        w2row[tid][4] = b.x; w2row[tid][5] = b.y; w2row[tid][6]  = b.z; w2row[tid][7]  = b.w;
        w2row[tid][8] = c.x; w2row[tid][9] = c.y; w2row[tid][10] = c.z; w2row[tid][11] = c.w;
      }
    }
    // no loop-end barrier: next step's count/h0n polls cover the
    // cross-wave LDS dependences (w1s/w2row/g0pre/g1bpre vs their readers).
  }

  // ---- final sampling (step E-1) ------------------------------------------
  if (bid == 0) {
    const unsigned tgt = 128u * (unsigned)E;
    while (__hip_atomic_load(cnt, __ATOMIC_RELAXED,
                             __HIP_MEMORY_SCOPE_SYSTEM) < tgt)
      __builtin_amdgcn_s_sleep(1);
    if (tid < OPS) {
      lgs[tid] = __hip_atomic_load(&LG[((E - 1) & 3) * OPS + tid],
                                   __ATOMIC_RELAXED, __HIP_MEMORY_SCOPE_SYSTEM);
    }
    __syncthreads();
    if (tid == 0) {
      float lgv[OPS];
#pragma unroll
      for (int o = 0; o < OPS; ++o)
        lgv[o] = (lgs[o] + cbl[(E - 1) * OPS + o]) * invt;
      float best = -1e30f; int act = 0;
#pragma unroll
      for (int o = 0; o < OPS; ++o) {
        float v = lgv[o] + gum[(E - 1) * OPS + o];
        if (v > best) { best = v; act = o; }
      }
      float mx = lgv[0];
#pragma unroll
      for (int o = 1; o < OPS; ++o) mx = fmaxf(mx, lgv[o]);
      float se = 0.f;
#pragma unroll
      for (int o = 0; o < OPS; ++o) se += expf(lgv[o] - mx);
      float logZ = mx + logf(se);
      float lp = lgv[act] - logZ;
      float ent = 0.f;
      for (int o = 0; o < OPS; ++o) {
        float l2 = lgv[o] - logZ;
        ent -= expf(l2) * l2;
      }
      out[E - 1]     = (float)act;
      out[2 * E - 1] = lp;
      out[3 * E - 1] = ent;
    }
  }
}

// ===========================================================================
extern "C" void kernel_launch(void* const* d_in, const int* in_sizes, int n_in,
                              void* d_out, int out_size, void* d_ws, size_t ws_size,
                              hipStream_t stream) {
  (void)out_size; (void)ws_size;
  float* out = (float*)d_out;
  float* ws  = (float*)d_ws;

  (void)hipGetLastError();

  static const long long expect[16] = {
      1, 1024, 1024, 1048576, 1048576, 2048, 2048,
      1048576, 1048576, 2048, 2048, 6144,
      29360128, 57344, 688128, 1344 };
  int bad = -1;
  if (n_in != 16) bad = 99;
  else {
    for (int i = 0; i < 16; ++i)
      if ((long long)in_sizes[i] != expect[i]) { bad = i; break; }
  }

  k_init<<<12, 256, 0, stream>>>((u64*)(ws + 16), (unsigned*)(ws + 8));
  if (bad >= 0) {
    k_diag<<<1, 64, 0, stream>>>(out, 80000.0f + (float)bad);
    return;
  }

  policy_persist<<<NWG, NT, 0, stream>>>(
      d_in[0],
      (const float*)d_in[1],  (const float*)d_in[2],
      (const float*)d_in[3],  (const float*)d_in[4],
      (const float*)d_in[5],  (const float*)d_in[6],
      (const float*)d_in[7],  (const float*)d_in[8],
      (const float*)d_in[9],  (const float*)d_in[10],
      (const float*)d_in[11], (const float*)d_in[12],
      (const float*)d_in[13], (const float*)d_in[14],
      (const float*)d_in[15],
      out, ws);

  hipError_t e = hipGetLastError();
  if (e != hipSuccess) {
    k_diag<<<1, 64, 0, stream>>>(out, 90000.0f + (float)(int)e);
  }
}

// Round 16
// 1083.793 us; speedup vs baseline: 1.4345x; 1.4345x over previous
//
#include <hip/hip_runtime.h>
#include <math.h>

#define H    512
#define OPS  12
#define E    112
#define NWG  128
#define NT   256

typedef unsigned long long u64;
typedef unsigned int u32x4 __attribute__((ext_vector_type(4)));

// ws layout: 16-float header | 3072 tagged u64
#define TW_HB0   0                    // [2][512] h0n
#define TW_HB1   1024                 // [2][512] h1n
#define TW_HMB   2048                 // [2][512] controller hidden
#define TW_TOTAL 3072

// bank-conflict-killing row rotation for h-vectors: word j lives at SW(j).
// Rotation amount is a multiple of 4 -> float4 groups stay contiguous and
// 16B-aligned; 32-stride readers spread across 8 bank windows (2-way, free).
#define SW(j) (((j) & ~31) | (((j) + ((((j) >> 5) & 7) << 2)) & 31))

__device__ __forceinline__ float sigf(float x) { return 1.f / (1.f + expf(-x)); }

// JAX threefry2x32, key = PRNGKey(42) = (0,42), 20 rounds
__device__ __forceinline__ void threefry_42(unsigned x0, unsigned x1,
                                            unsigned& o0, unsigned& o1) {
  const unsigned k0 = 0u, k1 = 42u;
  const unsigned k2 = k0 ^ k1 ^ 0x1BD11BDAu;
  x0 += k0; x1 += k1;
#define TF_R(rot) { x0 += x1; x1 = (x1 << rot) | (x1 >> (32 - rot)); x1 ^= x0; }
  TF_R(13) TF_R(15) TF_R(26) TF_R(6)
  x0 += k1; x1 += k2 + 1u;
  TF_R(17) TF_R(29) TF_R(16) TF_R(24)
  x0 += k2; x1 += k0 + 2u;
  TF_R(13) TF_R(15) TF_R(26) TF_R(6)
  x0 += k0; x1 += k1 + 3u;
  TF_R(17) TF_R(29) TF_R(16) TF_R(24)
  x0 += k1; x1 += k2 + 4u;
  TF_R(13) TF_R(15) TF_R(26) TF_R(6)
  x0 += k2; x1 += k0 + 5u;
#undef TF_R
  o0 = x0; o1 = x1;
}

__device__ __forceinline__ float bits_to_gumbel(unsigned bits) {
  unsigned fb = (bits >> 9) | 0x3f800000u;
  float u = __uint_as_float(fb) - 1.0f;
  u = u + 1.17549435e-38f;
  u = fmaxf(1.17549435e-38f, u);
  return -logf(-logf(u));
}

__device__ __forceinline__ float decode_temp(const void* temp_p) {
  float tf = *(const float*)temp_p;
  float a = fabsf(tf);
  if (a > 1e-6f && a < 1e6f) return tf;
  int ti = *(const int*)temp_p;
  if (ti != 0 && ti > -1000000 && ti < 1000000) return (float)ti;
  double td = *(const double*)temp_p;
  double ad = fabs(td);
  if (ad > 1e-6 && ad < 1e6) return (float)td;
  return 1.0f;
}

// MALL-coherent tagged-word transport (tag<<32 | float bits)
__device__ __forceinline__ void tag_store(u64* p, unsigned tag, float f) {
  u64 v = ((u64)tag << 32) | (u64)__float_as_uint(f);
  __hip_atomic_store(p, v, __ATOMIC_RELAXED, __HIP_MEMORY_SCOPE_SYSTEM);
}
// poll TWO adjacent tagged words with ONE 16B cache-bypassing load
__device__ __forceinline__ void tag_poll2(const u64* p, unsigned tag,
                                          float& f0, float& f1) {
  u32x4 v;
  for (;;) {
    asm volatile("global_load_dwordx4 %0, %1, off sc0 sc1\n\t"
                 "s_waitcnt vmcnt(0)"
                 : "=&v"(v) : "v"(p) : "memory");
    if (v.y == tag && v.w == tag) break;
    __builtin_amdgcn_s_sleep(1);
  }
  f0 = __uint_as_float(v.x);
  f1 = __uint_as_float(v.z);
}

__global__ void k_init(u64* tw) {
  int t = blockIdx.x * blockDim.x + threadIdx.x;
  if (t < TW_TOTAL) tw[t] = 0ull;
}
__global__ void k_diag(float* out, float v) {
  if (threadIdx.x == 0 && blockIdx.x == 0) out[0] = v;
}

// ===========================================================================
__global__ void __launch_bounds__(NT)
policy_persist(const void* temp_p,
               const float* __restrict__ h0_in, const float* __restrict__ c0_in,
               const float* __restrict__ Wih0,  const float* __restrict__ Whh0,
               const float* __restrict__ bih0,  const float* __restrict__ bhh0,
               const float* __restrict__ Wih1,  const float* __restrict__ Whh1,
               const float* __restrict__ bih1,  const float* __restrict__ bhh1,
               const float* __restrict__ emb,   const float* __restrict__ cW1,
               const float* __restrict__ cb1,   const float* __restrict__ cW2,
               const float* __restrict__ cb2,
               float* __restrict__ out, float* ws) {
  __shared__ __align__(16) float h0full[H], shp1[H], hm[H];
  __shared__ float g0pre[16], g1bpre[16], g1loc[16];
  __shared__ float ewloc[12 * 16], b0loc[16], b1loc[16];
  __shared__ float gum[E * OPS];
  __shared__ float w1s[512 * 5];          // W1[i] 4-col slice, stride-5
  __shared__ float w2s[512 * 13];         // W2[i], stride-13 (row-copied)
  __shared__ float c0loc[4], c1loc[4];
  __shared__ float spart[4][4];

  const int tid = threadIdx.x;
  const int bid = blockIdx.x;
  const int j0  = bid * 4;                       // owned h-columns
  const int cb  = (bid & 7) * 16 + (bid >> 3);   // XCD-grouped HM col-block
  const float invt = 1.f / decode_temp(temp_p);

  u64* HB0 = (u64*)(ws + 16) + TW_HB0;
  u64* HB1 = (u64*)(ws + 16) + TW_HB1;
  u64* HMB = (u64*)(ws + 16) + TW_HMB;

  // ---------------- setup (all WG-local) -----------------------------------
  for (int p = tid; p < E * OPS; p += NT) {
    unsigned y0, y1;
    threefry_42(0u, (unsigned)p, y0, y1);
    gum[p] = bits_to_gumbel(y0 ^ y1);
  }
  for (int j = tid; j < H; j += NT) {
    h0full[SW(j)] = h0_in[j];
    shp1[SW(j)]   = h0_in[H + j];
  }
  if (tid < 192) {
    int a = tid / 16, ridx = tid % 16;
    int g = ridx >> 2, dj = ridx & 3;
    int row = g * H + j0 + dj;
    const float* er = emb + a * H;
    const float* wr = Wih0 + (size_t)row * H;
    float acc = 0.f;
    for (int k = 0; k < H; k += 4) {
      float4 e4 = *(const float4*)(er + k);
      float4 w4 = *(const float4*)(wr + k);
      acc += e4.x * w4.x + e4.y * w4.y + e4.z * w4.z + e4.w * w4.w;
    }
    ewloc[tid] = acc;
  }
  if (tid < 16) {
    int g = tid >> 2, dj = tid & 3;
    int row = g * H + j0 + dj;
    b0loc[tid] = bih0[row] + bhh0[row];
    b1loc[tid] = bih1[row] + bhh1[row];
  }
  if (tid < 4) {
    c0loc[tid] = c0_in[j0 + tid];
    c1loc[tid] = c0_in[H + j0 + tid];
  }
  __syncthreads();

  // G-pre(0) combined pass + W1[0] prefetch (round-9 math, swizzled reads)
  {
    int rowidx = tid >> 3, lane = tid & 7;
    int cell = rowidx >> 4, ridx = rowidx & 15;
    int g = ridx >> 2, dj = ridx & 3;
    int row = g * H + j0 + dj;
    const float* wr = (cell ? Whh1 : Whh0) + (size_t)row * H + lane * 64;
    const float* hv = cell ? shp1 : h0full;
    float acc = 0.f;
#pragma unroll
    for (int k = 0; k < 64; k += 4) {
      float4 w4 = *(const float4*)(wr + k);
      float4 h4 = *(const float4*)&hv[SW(lane * 64 + k)];
      acc += w4.x * h4.x + w4.y * h4.y + w4.z * h4.z + w4.w * h4.w;
    }
    acc += __shfl_xor(acc, 1);
    acc += __shfl_xor(acc, 2);
    acc += __shfl_xor(acc, 4);
    if (lane == 0) {
      if (cell == 0) g0pre[ridx] = acc + b0loc[ridx];
      else           g1bpre[ridx] = acc;
    }
    const float* wb = cW1 + (size_t)cb * 4;
    float4 r0 = *(const float4*)(wb + (size_t)tid * H);
    float4 r1 = *(const float4*)(wb + (size_t)(tid + 256) * H);
    int k0 = tid * 5, k1 = (tid + 256) * 5;
    w1s[k0] = r0.x; w1s[k0 + 1] = r0.y; w1s[k0 + 2] = r0.z; w1s[k0 + 3] = r0.w;
    w1s[k1] = r1.x; w1s[k1 + 1] = r1.y; w1s[k1 + 2] = r1.z; w1s[k1 + 3] = r1.w;
  }
  __syncthreads();

#pragma unroll 1
  for (int i = 0; i < E; ++i) {
    const int p = i & 1;
    const unsigned tg = (unsigned)(i + 1);

    // ---- 1: sample step i-1; PW0 + h0n store issued BEFORE logZ/lp/ent ----
    if (i > 0) {
      const int q = (i - 1) & 1;
      int t2 = tid * 2;
      tag_poll2(&HMB[q * 512 + t2], (unsigned)i, hm[t2], hm[t2 + 1]);
      __syncthreads();
      if (tid < 64) {
        float lg[OPS];
#pragma unroll
        for (int o = 0; o < OPS; ++o) lg[o] = 0.f;
#pragma unroll
        for (int jj = 0; jj < 8; ++jj) {
          int j = jj * 64 + tid;
          float hmv = hm[j];
          const float* w2r = &w2s[j * 13];
#pragma unroll
          for (int o = 0; o < OPS; ++o) lg[o] += hmv * w2r[o];
        }
#pragma unroll
        for (int s = 1; s < 64; s <<= 1) {
#pragma unroll
          for (int o = 0; o < OPS; ++o) lg[o] += __shfl_xor(lg[o], s);
        }
#pragma unroll
        for (int o = 0; o < OPS; ++o) lg[o] = (lg[o] + cb2[(i - 1) * OPS + o]) * invt;
        // argmax FIRST (lg identical across lanes after reduce; gum is LDS)
        float best = -1e30f; int act = 0;
#pragma unroll
        for (int o = 0; o < OPS; ++o) {
          float v = lg[o] + gum[(i - 1) * OPS + o];
          if (v > best) { best = v; act = o; }
        }
        // PW0 (lanes 0-3) + h0n tagged store — critical path head
        if (tid < 4) {
          float gi = g0pre[tid]      + ewloc[act * 16 + tid];
          float gf = g0pre[4 + tid]  + ewloc[act * 16 + 4 + tid];
          float gg = g0pre[8 + tid]  + ewloc[act * 16 + 8 + tid];
          float go = g0pre[12 + tid] + ewloc[act * 16 + 12 + tid];
          float cn = sigf(gf) * c0loc[tid] + sigf(gi) * tanhf(gg);
          c0loc[tid] = cn;
          tag_store(&HB0[p * 512 + j0 + tid], tg, sigf(go) * tanhf(cn));
        }
        // lp/ent/out — off the chain, bid 0 only
        if (bid == 0) {
          float mx = lg[0];
#pragma unroll
          for (int o = 1; o < OPS; ++o) mx = fmaxf(mx, lg[o]);
          float se = 0.f;
#pragma unroll
          for (int o = 0; o < OPS; ++o) se += expf(lg[o] - mx);
          float logZ = mx + logf(se);
          if (tid == 0) {
            float lp = lg[act] - logZ;
            float ent = 0.f;
            for (int o = 0; o < OPS; ++o) {
              float l2 = lg[o] - logZ;
              ent -= expf(l2) * l2;
            }
            out[i - 1]         = (float)act;
            out[E + i - 1]     = lp;
            out[2 * E + i - 1] = ent;
          }
        }
      }
      // no barrier: everything above is wave-0-internal
    } else {
      // i == 0: PW0 without embedding contribution
      if (tid < 4) {
        float gi = g0pre[tid];
        float gf = g0pre[4 + tid];
        float gg = g0pre[8 + tid];
        float go = g0pre[12 + tid];
        float cn = sigf(gf) * c0loc[tid] + sigf(gi) * tanhf(gg);
        c0loc[tid] = cn;
        tag_store(&HB0[p * 512 + j0 + tid], tg, sigf(go) * tanhf(cn));
      }
    }

    // ---- 3: poll full h0n (swizzled LDS commit) ---------------------------
    {
      int t2 = tid * 2;
      int sw = SW(t2);                   // pair stays adjacent (t2 even)
      tag_poll2(&HB0[p * 512 + t2], tg, h0full[sw], h0full[sw + 1]);
    }
    __syncthreads();

    // ---- 4: G1 = Wih1@h0n + G1Bpre + B1 (own 16 rows, 16 lanes/row) -------
    {
      int ridx = tid >> 4, lane = tid & 15;
      int g = ridx >> 2, dj = ridx & 3;
      int row = g * H + j0 + dj;
      const float* wr = Wih1 + (size_t)row * H + lane * 32;
      float acc = 0.f;
#pragma unroll
      for (int k = 0; k < 32; k += 4) {
        float4 w4 = *(const float4*)(wr + k);
        float4 h4 = *(const float4*)&h0full[SW(lane * 32 + k)];
        acc += w4.x * h4.x + w4.y * h4.y + w4.z * h4.z + w4.w * h4.w;
      }
      acc += __shfl_xor(acc, 1);
      acc += __shfl_xor(acc, 2);
      acc += __shfl_xor(acc, 4);
      acc += __shfl_xor(acc, 8);
      if (lane == 0) g1loc[ridx] = acc + g1bpre[ridx] + b1loc[ridx];
    }
    __syncthreads();

    // ---- 5: PW1 (own 4 cols) -> tagged h1n store --------------------------
    if (tid < 4) {
      float gi = g1loc[tid];
      float gf = g1loc[4 + tid];
      float gg = g1loc[8 + tid];
      float go = g1loc[12 + tid];
      float cn = sigf(gf) * c1loc[tid] + sigf(gi) * tanhf(gg);
      c1loc[tid] = cn;
      tag_store(&HB1[p * 512 + j0 + tid], tg, sigf(go) * tanhf(cn));
    }

    // ---- 6: shadow-1: issue W1[i+1] loads; G0pre(i+1); W2[i] -> w2s -------
    float4 v0, v1;
    if (i + 1 < E) {
      const float* wb = cW1 + (size_t)(i + 1) * H * H + (size_t)cb * 4;
      v0 = *(const float4*)(wb + (size_t)tid * H);
      v1 = *(const float4*)(wb + (size_t)(tid + 256) * H);
    }
    if (tid < 128) {
      int ridx = tid >> 3, lane = tid & 7;
      int g = ridx >> 2, dj = ridx & 3;
      int row = g * H + j0 + dj;
      const float* wr = Whh0 + (size_t)row * H + lane * 64;
      float acc = 0.f;
#pragma unroll
      for (int k = 0; k < 64; k += 4) {
        float4 w4 = *(const float4*)(wr + k);
        float4 h4 = *(const float4*)&h0full[SW(lane * 64 + k)];
        acc += w4.x * h4.x + w4.y * h4.y + w4.z * h4.z + w4.w * h4.w;
      }
      acc += __shfl_xor(acc, 1);
      acc += __shfl_xor(acc, 2);
      acc += __shfl_xor(acc, 4);
      if (lane == 0) g0pre[ridx] = acc + b0loc[ridx];
    }
    {
      // W2[i] staging: thread t copies rows 2t, 2t+1 (12 floats each).
      // LDS writes at 13*row are 2-way bank-aliased (free); values and the
      // w2s layout are identical to before — only the write pattern changed.
      const float* wsrc = cW2 + (size_t)i * H * OPS;
#pragma unroll
      for (int rr = 0; rr < 2; ++rr) {
        int r = tid * 2 + rr;
        const float* s = wsrc + r * 12;
        float4 a = *(const float4*)(s);
        float4 b = *(const float4*)(s + 4);
        float4 c = *(const float4*)(s + 8);
        float* d = &w2s[r * 13];
        d[0] = a.x; d[1] = a.y; d[2]  = a.z; d[3]  = a.w;
        d[4] = b.x; d[5] = b.y; d[6]  = b.z; d[7]  = b.w;
        d[8] = c.x; d[9] = c.y; d[10] = c.z; d[11] = c.w;
      }
    }

    // ---- 7: poll full h1n (swizzled LDS commit) ---------------------------
    {
      int t2 = tid * 2;
      int sw = SW(t2);
      tag_poll2(&HB1[p * 512 + t2], tg, shp1[sw], shp1[sw + 1]);
    }
    __syncthreads();

    // ---- 8: phase C: HM own 4 cols from LDS W1 ----------------------------
    {
      int wv = tid >> 6, ln = tid & 63;
      int jl = ln & 3, ks = ln >> 2;
      int kbase = wv * 128 + ks * 8;
      float acc = 0.f;
#pragma unroll
      for (int t = 0; t < 8; ++t) {
        int k = kbase + t;
        acc += shp1[SW(k)] * w1s[k * 5 + jl];
      }
      acc += __shfl_xor(acc, 4);
      acc += __shfl_xor(acc, 8);
      acc += __shfl_xor(acc, 16);
      acc += __shfl_xor(acc, 32);
      if (ln < 4) spart[wv][ln] = acc;
    }
    __syncthreads();
    if (tid < 4) {
      float s = spart[0][tid] + spart[1][tid] + spart[2][tid] + spart[3][tid];
      s += cb1[(size_t)i * H + cb * 4 + tid];
      tag_store(&HMB[p * 512 + cb * 4 + tid], tg, fmaxf(s, 0.f));
    }

    // ---- 9: shadow-2: G1Bpre(i+1); commit W1[i+1] -> w1s ------------------
    if (i + 1 < E) {
      if (tid < 128) {
        int ridx = tid >> 3, lane = tid & 7;
        int g = ridx >> 2, dj = ridx & 3;
        int row = g * H + j0 + dj;
        const float* wr = Whh1 + (size_t)row * H + lane * 64;
        float acc = 0.f;
#pragma unroll
        for (int k = 0; k < 64; k += 4) {
          float4 w4 = *(const float4*)(wr + k);
          float4 h4 = *(const float4*)&shp1[SW(lane * 64 + k)];
          acc += w4.x * h4.x + w4.y * h4.y + w4.z * h4.z + w4.w * h4.w;
        }
        acc += __shfl_xor(acc, 1);
        acc += __shfl_xor(acc, 2);
        acc += __shfl_xor(acc, 4);
        if (lane == 0) g1bpre[ridx] = acc;
      }
      int k0 = tid * 5, k1 = (tid + 256) * 5;
      w1s[k0] = v0.x; w1s[k0 + 1] = v0.y; w1s[k0 + 2] = v0.z; w1s[k0 + 3] = v0.w;
      w1s[k1] = v1.x; w1s[k1 + 1] = v1.y; w1s[k1 + 2] = v1.z; w1s[k1 + 3] = v1.w;
    }
    // no loop-end barrier: next step's HM/h0n poll barriers cover all
    // cross-wave LDS dependences (w1s/w2s/g0pre/g1bpre vs their readers).
  }

  // ---- final sampling (step E-1); w2s = W2[E-1] ---------------------------
  if (bid == 0) {
    const int q = (E - 1) & 1;
    int t2 = tid * 2;
    tag_poll2(&HMB[q * 512 + t2], (unsigned)E, hm[t2], hm[t2 + 1]);
    __syncthreads();
    if (tid < 64) {
      float lg[OPS];
#pragma unroll
      for (int o = 0; o < OPS; ++o) lg[o] = 0.f;
#pragma unroll
      for (int jj = 0; jj < 8; ++jj) {
        int j = jj * 64 + tid;
        float hmv = hm[j];
        const float* w2r = &w2s[j * 13];
#pragma unroll
        for (int o = 0; o < OPS; ++o) lg[o] += hmv * w2r[o];
      }
#pragma unroll
      for (int s = 1; s < 64; s <<= 1) {
#pragma unroll
        for (int o = 0; o < OPS; ++o) lg[o] += __shfl_xor(lg[o], s);
      }
#pragma unroll
      for (int o = 0; o < OPS; ++o) lg[o] = (lg[o] + cb2[(E - 1) * OPS + o]) * invt;
      float mx = lg[0];
#pragma unroll
      for (int o = 1; o < OPS; ++o) mx = fmaxf(mx, lg[o]);
      float se = 0.f;
#pragma unroll
      for (int o = 0; o < OPS; ++o) se += expf(lg[o] - mx);
      float logZ = mx + logf(se);
      float best = -1e30f; int act = 0;
#pragma unroll
      for (int o = 0; o < OPS; ++o) {
        float v = lg[o] + gum[(E - 1) * OPS + o];
        if (v > best) { best = v; act = o; }
      }
      if (tid == 0) {
        float lp = lg[act] - logZ;
        float ent = 0.f;
        for (int o = 0; o < OPS; ++o) {
          float l2 = lg[o] - logZ;
          ent -= expf(l2) * l2;
        }
        out[E - 1]     = (float)act;
        out[2 * E - 1] = lp;
        out[3 * E - 1] = ent;
      }
    }
  }
}

// ===========================================================================
extern "C" void kernel_launch(void* const* d_in, const int* in_sizes, int n_in,
                              void* d_out, int out_size, void* d_ws, size_t ws_size,
                              hipStream_t stream) {
  (void)out_size; (void)ws_size;
  float* out = (float*)d_out;
  float* ws  = (float*)d_ws;

  (void)hipGetLastError();

  static const long long expect[16] = {
      1, 1024, 1024, 1048576, 1048576, 2048, 2048,
      1048576, 1048576, 2048, 2048, 6144,
      29360128, 57344, 688128, 1344 };
  int bad = -1;
  if (n_in != 16) bad = 99;
  else {
    for (int i = 0; i < 16; ++i)
      if ((long long)in_sizes[i] != expect[i]) { bad = i; break; }
  }

  k_init<<<12, 256, 0, stream>>>((u64*)(ws + 16));
  if (bad >= 0) {
    k_diag<<<1, 64, 0, stream>>>(out, 80000.0f + (float)bad);
    return;
  }

  policy_persist<<<NWG, NT, 0, stream>>>(
      d_in[0],
      (const float*)d_in[1],  (const float*)d_in[2],
      (const float*)d_in[3],  (const float*)d_in[4],
      (const float*)d_in[5],  (const float*)d_in[6],
      (const float*)d_in[7],  (const float*)d_in[8],
      (const float*)d_in[9],  (const float*)d_in[10],
      (const float*)d_in[11], (const float*)d_in[12],
      (const float*)d_in[13], (const float*)d_in[14],
      (const float*)d_in[15],
      out, ws);

  hipError_t e = hipGetLastError();
  if (e != hipSuccess) {
    k_diag<<<1, 64, 0, stream>>>(out, 90000.0f + (float)(int)e);
  }
}